// Round 7
// baseline (393.309 us; speedup 1.0000x reference)
//
#include <hip/hip_runtime.h>
#include <hip/hip_cooperative_groups.h>
#include <math.h>

namespace cg = cooperative_groups;

// GCN 2-layer. R7: all 8 phases fused into one cooperative kernel with
// grid.sync() between phases (removes inter-dispatch gaps + per-phase setup).
// Atomic floor model: 5 LDS-atomic ops/edge @ ~3.7cyc = ~96us/256CU.
// Fallback chain: coop launch error -> R6 8-kernel pipeline -> R1 atomic pipeline.

#define NPB 256        // nodes per bucket (power of 2)
#define SHIFT 8        // log2(NPB)
#define NB_MAX 512     // max buckets supported by LDS hist arrays
#define SPLIT 8        // sub-blocks per bucket in partial phases
#define T1 512         // threads per block
#define EPT 8          // edges staged per thread in bin phase

#define FSCALE 1024.0f     // fixed-point scale (2^10)
#define FBIAS  8192        // per-addend bias (2^13)
#define FMASK  0x1FFFFFu   // 21-bit field mask

static __device__ __forceinline__ long long load_idx(const void* edges, long long pos, int is64) {
    if (is64) return ((const long long*)edges)[pos];
    return (long long)((const int*)edges)[pos];
}

static __device__ __forceinline__ unsigned long long pack3(float x, float y, float z) {
    unsigned long long e0 = (unsigned)(__float2int_rn(x * FSCALE) + FBIAS);
    unsigned long long e1 = (unsigned)(__float2int_rn(y * FSCALE) + FBIAS);
    unsigned long long e2 = (unsigned)(__float2int_rn(z * FSCALE) + FBIAS);
    return e0 | (e1 << 21) | (e2 << 42);
}

static __device__ __forceinline__ void sub_range(int cnt, int sub, int* lo, int* hi) {
    int l = (int)(((long long)cnt * sub / SPLIT) & ~3LL);
    int h = (sub == SPLIT - 1) ? cnt : (int)(((long long)cnt * (sub + 1) / SPLIT) & ~3LL);
    *lo = l; *hi = h;
}

// ================= fused cooperative kernel =================
__global__ void __launch_bounds__(T1, 4)
k_fused(const float* __restrict__ x, const void* __restrict__ ei,
        const float* __restrict__ W1, const float* __restrict__ b1,
        const float* __restrict__ W2, const float* __restrict__ b2,
        float* __restrict__ out, long long n, long long E, int nb, int cap,
        float4* __restrict__ xs, unsigned long long* __restrict__ part,
        unsigned int* __restrict__ bin, float* __restrict__ dinv,
        float* __restrict__ gs, int* __restrict__ cursor, int* __restrict__ flag) {
    cg::grid_group grid = cg::this_grid();
    const int tid = threadIdx.x;
    const int bid = blockIdx.x;
    const int G = gridDim.x;

    __shared__ int hist[NB_MAX];
    __shared__ int base[NB_MAX];
    __shared__ unsigned long long accll[NPB];   // aliased per phase
    __shared__ int lflag;
    int*   dcnt = (int*)accll;
    float* facc = (float*)accll;

    // ---- P0: zero cursors + dtype detect ----
    for (int i = bid * T1 + tid; i < nb; i += G * T1) cursor[i] = 0;
    if (bid == 0 && tid == 0) {
        const int* e32 = (const int*)ei;
        int is64 = 1;
        for (int k = 0; k < 16; ++k)
            if (e32[2 * k + 1] != 0) { is64 = 0; break; }
        *flag = is64;
    }
    grid.sync();

    if (tid == 0) lflag = *flag;
    __syncthreads();
    const int is64 = lflag;

    // ---- P1: bin (register-staged, tiles of T1*EPT edges) ----
    const long long per_tile = (long long)T1 * EPT;
    const long long ntile = (E + per_tile - 1) / per_tile;
    for (long long t = bid; t < ntile; t += G) {
        for (int b = tid; b < nb; b += T1) hist[b] = 0;
        __syncthreads();
        const long long start = t * per_tile;
        unsigned es[EPT], ed[EPT];
        if (is64) {
            const long long* e64 = (const long long*)ei;
#pragma unroll
            for (int j = 0; j < EPT; ++j) {
                long long e = start + j * T1 + tid;
                if (e < E) { es[j] = (unsigned)e64[e]; ed[j] = (unsigned)e64[E + e]; }
                else ed[j] = 0xFFFFFFFFu;
            }
        } else {
            const int* e32 = (const int*)ei;
#pragma unroll
            for (int j = 0; j < EPT; ++j) {
                long long e = start + j * T1 + tid;
                if (e < E) { es[j] = (unsigned)e32[e]; ed[j] = (unsigned)e32[E + e]; }
                else ed[j] = 0xFFFFFFFFu;
            }
        }
#pragma unroll
        for (int j = 0; j < EPT; ++j)
            if (ed[j] != 0xFFFFFFFFu) atomicAdd(&hist[ed[j] >> SHIFT], 1);
        __syncthreads();
        for (int b = tid; b < nb; b += T1) {
            int h = hist[b];
            base[b] = h ? atomicAdd(&cursor[b], h) : 0;
            hist[b] = 0;
        }
        __syncthreads();
#pragma unroll
        for (int j = 0; j < EPT; ++j) {
            if (ed[j] == 0xFFFFFFFFu) continue;
            int bk = (int)(ed[j] >> SHIFT);
            int off = base[bk] + atomicAdd(&hist[bk], 1);
            if (off < cap)
                bin[(long long)bk * cap + off] = ((ed[j] & (NPB - 1)) << 17) | es[j];
        }
        __syncthreads();   // protect hist before next tile's zero
    }
    grid.sync();

    // ---- P2: degree partial counts ----
    const int ntask = nb * SPLIT;
    int* parti = (int*)part;
    for (int task = bid; task < ntask; task += G) {
        if (tid < NPB) dcnt[tid] = 0;
        __syncthreads();
        const int bk = task >> 3;
        const int sub = task & (SPLIT - 1);
        const int cnt = min(cursor[bk], cap);
        int lo, hi; sub_range(cnt, sub, &lo, &hi);
        const unsigned int* bp = bin + (long long)bk * cap;
        const int len = hi - lo, nvec = len >> 2;
        const uint4* bp4 = (const uint4*)(bp + lo);
        for (int v = tid; v < nvec; v += T1) {
            uint4 q = bp4[v];
            atomicAdd(&dcnt[q.x >> 17], 1);
            atomicAdd(&dcnt[q.y >> 17], 1);
            atomicAdd(&dcnt[q.z >> 17], 1);
            atomicAdd(&dcnt[q.w >> 17], 1);
        }
        for (int k = lo + (nvec << 2) + tid; k < hi; k += T1)
            atomicAdd(&dcnt[bp[k] >> 17], 1);
        __syncthreads();
        if (tid < NPB) parti[(long long)task * NPB + tid] = dcnt[tid];
        __syncthreads();
    }
    grid.sync();

    // ---- P3: combine deg -> dinv, pre-scaled xs (xs.w = edge-degree) ----
    for (long long i = (long long)bid * T1 + tid; i < n; i += (long long)G * T1) {
        int bk = (int)(i >> SHIFT), lc = (int)(i & (NPB - 1));
        int degE = 0;
#pragma unroll
        for (int s = 0; s < SPLIT; ++s)
            degE += parti[(long long)(bk * SPLIT + s) * NPB + lc];
        float di = rsqrtf((float)degE + 1.0f);
        dinv[i] = di;
        xs[i] = make_float4(x[3 * i] * di, x[3 * i + 1] * di, x[3 * i + 2] * di, (float)degE);
    }
    grid.sync();

    // ---- P4: layer-1 partials, one packed u64 LDS atomic per edge ----
    for (int task = bid; task < ntask; task += G) {
        if (tid < NPB) accll[tid] = 0ull;
        __syncthreads();
        const int bk = task >> 3;
        const int sub = task & (SPLIT - 1);
        const int cnt = min(cursor[bk], cap);
        int lo, hi; sub_range(cnt, sub, &lo, &hi);
        const unsigned int* bp = bin + (long long)bk * cap;
        const int len = hi - lo, nvec = len >> 2;
        const uint4* bp4 = (const uint4*)(bp + lo);
        for (int v = tid; v < nvec; v += T1) {
            uint4 q = bp4[v];
            float4 v0 = xs[q.x & 0x1FFFFu];
            float4 v1 = xs[q.y & 0x1FFFFu];
            float4 v2 = xs[q.z & 0x1FFFFu];
            float4 v3 = xs[q.w & 0x1FFFFu];
            atomicAdd(&accll[q.x >> 17], pack3(v0.x, v0.y, v0.z));
            atomicAdd(&accll[q.y >> 17], pack3(v1.x, v1.y, v1.z));
            atomicAdd(&accll[q.z >> 17], pack3(v2.x, v2.y, v2.z));
            atomicAdd(&accll[q.w >> 17], pack3(v3.x, v3.y, v3.z));
        }
        for (int k = lo + (nvec << 2) + tid; k < hi; k += T1) {
            unsigned p = bp[k];
            float4 v = xs[p & 0x1FFFFu];
            atomicAdd(&accll[p >> 17], pack3(v.x, v.y, v.z));
        }
        __syncthreads();
        if (tid < NPB) part[(long long)task * NPB + tid] = accll[tid];
        __syncthreads();
    }
    grid.sync();

    // ---- P5: combine + fused 3->16->relu->1 MLP -> gs ----
    for (long long i = (long long)bid * T1 + tid; i < n; i += (long long)G * T1) {
        int bk = (int)(i >> SHIFT), lc = (int)(i & (NPB - 1));
        int f0 = 0, f1 = 0, f2 = 0;
#pragma unroll
        for (int s = 0; s < SPLIT; ++s) {
            unsigned long long p = part[(long long)(bk * SPLIT + s) * NPB + lc];
            f0 += (int)(p & FMASK);
            f1 += (int)((p >> 21) & FMASK);
            f2 += (int)((p >> 42) & FMASK);
        }
        float4 self = xs[i];
        int degE = (int)self.w;
        const float inv = 1.0f / FSCALE;
        float a0 = (float)(f0 - FBIAS * degE) * inv + self.x;
        float a1 = (float)(f1 - FBIAS * degE) * inv + self.y;
        float a2 = (float)(f2 - FBIAS * degE) * inv + self.z;
        float di = dinv[i];
        a0 *= di; a1 *= di; a2 *= di;
        float g = 0.0f;
#pragma unroll
        for (int c = 0; c < 16; ++c) {   // W1 [3,16] row-major
            float h = fmaf(a0, W1[c], fmaf(a1, W1[16 + c], fmaf(a2, W1[32 + c], b1[c])));
            h = fmaxf(h, 0.0f);
            g = fmaf(h, W2[c], g);
        }
        gs[i] = g * di;
    }
    grid.sync();

    // ---- P6: layer-2 scalar partials ----
    float* partf = (float*)part;
    for (int task = bid; task < ntask; task += G) {
        if (tid < NPB) facc[tid] = 0.0f;
        __syncthreads();
        const int bk = task >> 3;
        const int sub = task & (SPLIT - 1);
        const int cnt = min(cursor[bk], cap);
        int lo, hi; sub_range(cnt, sub, &lo, &hi);
        const unsigned int* bp = bin + (long long)bk * cap;
        const int len = hi - lo, nvec = len >> 2;
        const uint4* bp4 = (const uint4*)(bp + lo);
        for (int v = tid; v < nvec; v += T1) {
            uint4 q = bp4[v];
            float g0 = gs[q.x & 0x1FFFFu];
            float g1 = gs[q.y & 0x1FFFFu];
            float g2 = gs[q.z & 0x1FFFFu];
            float g3 = gs[q.w & 0x1FFFFu];
            atomicAdd(&facc[q.x >> 17], g0);
            atomicAdd(&facc[q.y >> 17], g1);
            atomicAdd(&facc[q.z >> 17], g2);
            atomicAdd(&facc[q.w >> 17], g3);
        }
        for (int k = lo + (nvec << 2) + tid; k < hi; k += T1) {
            unsigned p = bp[k];
            atomicAdd(&facc[p >> 17], gs[p & 0x1FFFFu]);
        }
        __syncthreads();
        if (tid < NPB) partf[(long long)task * NPB + tid] = facc[tid];
        __syncthreads();
    }
    grid.sync();

    // ---- P7: combine + sigmoid -> out ----
    for (long long i = (long long)bid * T1 + tid; i < n; i += (long long)G * T1) {
        int bk = (int)(i >> SHIFT), lc = (int)(i & (NPB - 1));
        float acc = gs[i];
#pragma unroll
        for (int s = 0; s < SPLIT; ++s)
            acc += partf[(long long)(bk * SPLIT + s) * NPB + lc];
        float z = dinv[i] * acc + b2[0];
        out[i] = 1.0f / (1.0f + expf(-z));
    }
}

// ================= R6 pipeline (fallback if coop launch fails) =================
__global__ void k_zero_cursor(int* cursor, int nb, const int* e32, int* flag) {
    int i = blockIdx.x * blockDim.x + threadIdx.x;
    if (i < nb) cursor[i] = 0;
    if (i == 0) {
        int is64 = 1;
        for (int k = 0; k < 16; ++k)
            if (e32[2 * k + 1] != 0) { is64 = 0; break; }
        *flag = is64;
    }
}

__global__ void k_bin(const void* edges, const int* __restrict__ flag,
                      int* __restrict__ cursor, unsigned int* __restrict__ bin,
                      long long E, int nb, int cap) {
    __shared__ int hist[NB_MAX];
    __shared__ int base[NB_MAX];
    const int tid = threadIdx.x;
    for (int b = tid; b < nb; b += T1) hist[b] = 0;
    __syncthreads();
    const int is64 = *flag;
    const long long start = (long long)blockIdx.x * (T1 * EPT);
    unsigned es[EPT], ed[EPT];
    if (is64) {
        const long long* e64 = (const long long*)edges;
#pragma unroll
        for (int j = 0; j < EPT; ++j) {
            long long e = start + j * T1 + tid;
            if (e < E) { es[j] = (unsigned)e64[e]; ed[j] = (unsigned)e64[E + e]; }
            else ed[j] = 0xFFFFFFFFu;
        }
    } else {
        const int* e32 = (const int*)edges;
#pragma unroll
        for (int j = 0; j < EPT; ++j) {
            long long e = start + j * T1 + tid;
            if (e < E) { es[j] = (unsigned)e32[e]; ed[j] = (unsigned)e32[E + e]; }
            else ed[j] = 0xFFFFFFFFu;
        }
    }
#pragma unroll
    for (int j = 0; j < EPT; ++j)
        if (ed[j] != 0xFFFFFFFFu) atomicAdd(&hist[ed[j] >> SHIFT], 1);
    __syncthreads();
    for (int b = tid; b < nb; b += T1) {
        int h = hist[b];
        base[b] = h ? atomicAdd(&cursor[b], h) : 0;
        hist[b] = 0;
    }
    __syncthreads();
#pragma unroll
    for (int j = 0; j < EPT; ++j) {
        if (ed[j] == 0xFFFFFFFFu) continue;
        int bk = (int)(ed[j] >> SHIFT);
        int off = base[bk] + atomicAdd(&hist[bk], 1);
        if (off < cap)
            bin[(long long)bk * cap + off] = ((ed[j] & (NPB - 1)) << 17) | es[j];
    }
}

__global__ void k_degP(const unsigned int* __restrict__ bin, const int* __restrict__ cursor,
                       int* __restrict__ part, int cap) {
    __shared__ int dcnt[NPB];
    const int tid = threadIdx.x;
    dcnt[tid] = 0;
    __syncthreads();
    const int bk = blockIdx.x >> 3;
    const int sub = blockIdx.x & (SPLIT - 1);
    const int cnt = min(cursor[bk], cap);
    int lo, hi; sub_range(cnt, sub, &lo, &hi);
    const unsigned int* bp = bin + (long long)bk * cap;
    const int len = hi - lo, nvec = len >> 2;
    const uint4* bp4 = (const uint4*)(bp + lo);
    for (int v = tid; v < nvec; v += NPB) {
        uint4 q = bp4[v];
        atomicAdd(&dcnt[q.x >> 17], 1);
        atomicAdd(&dcnt[q.y >> 17], 1);
        atomicAdd(&dcnt[q.z >> 17], 1);
        atomicAdd(&dcnt[q.w >> 17], 1);
    }
    for (int k = lo + (nvec << 2) + tid; k < hi; k += NPB)
        atomicAdd(&dcnt[bp[k] >> 17], 1);
    __syncthreads();
    part[(long long)blockIdx.x * NPB + tid] = dcnt[tid];
}

__global__ void k_degC(const int* __restrict__ part, const float* __restrict__ x,
                       float* __restrict__ dinv, float4* __restrict__ xs, int n) {
    const int tid = threadIdx.x;
    const int bk = blockIdx.x;
    const int i = bk * NPB + tid;
    if (i >= n) return;
    int degE = 0;
#pragma unroll
    for (int s = 0; s < SPLIT; ++s)
        degE += part[(long long)(bk * SPLIT + s) * NPB + tid];
    float di = rsqrtf((float)degE + 1.0f);
    dinv[i] = di;
    xs[i] = make_float4(x[3 * i] * di, x[3 * i + 1] * di, x[3 * i + 2] * di, (float)degE);
}

__global__ void k_agg1P(const unsigned int* __restrict__ bin, const int* __restrict__ cursor,
                        const float4* __restrict__ xs, unsigned long long* __restrict__ part,
                        int cap) {
    __shared__ unsigned long long acc[NPB];
    const int tid = threadIdx.x;
    acc[tid] = 0ull;
    __syncthreads();
    const int bk = blockIdx.x >> 3;
    const int sub = blockIdx.x & (SPLIT - 1);
    const int cnt = min(cursor[bk], cap);
    int lo, hi; sub_range(cnt, sub, &lo, &hi);
    const unsigned int* bp = bin + (long long)bk * cap;
    const int len = hi - lo, nvec = len >> 2;
    const uint4* bp4 = (const uint4*)(bp + lo);
    for (int v = tid; v < nvec; v += NPB) {
        uint4 q = bp4[v];
        float4 v0 = xs[q.x & 0x1FFFFu];
        float4 v1 = xs[q.y & 0x1FFFFu];
        float4 v2 = xs[q.z & 0x1FFFFu];
        float4 v3 = xs[q.w & 0x1FFFFu];
        atomicAdd(&acc[q.x >> 17], pack3(v0.x, v0.y, v0.z));
        atomicAdd(&acc[q.y >> 17], pack3(v1.x, v1.y, v1.z));
        atomicAdd(&acc[q.z >> 17], pack3(v2.x, v2.y, v2.z));
        atomicAdd(&acc[q.w >> 17], pack3(v3.x, v3.y, v3.z));
    }
    for (int k = lo + (nvec << 2) + tid; k < hi; k += NPB) {
        unsigned p = bp[k];
        float4 v = xs[p & 0x1FFFFu];
        atomicAdd(&acc[p >> 17], pack3(v.x, v.y, v.z));
    }
    __syncthreads();
    part[(long long)blockIdx.x * NPB + tid] = acc[tid];
}

__global__ void k_agg1C(const unsigned long long* __restrict__ part,
                        const float* __restrict__ dinv, const float4* __restrict__ xs,
                        const float* __restrict__ W1, const float* __restrict__ b1,
                        const float* __restrict__ W2, float* __restrict__ gs, int n) {
    const int tid = threadIdx.x;
    const int bk = blockIdx.x;
    const int i = bk * NPB + tid;
    if (i >= n) return;
    int f0 = 0, f1 = 0, f2 = 0;
#pragma unroll
    for (int s = 0; s < SPLIT; ++s) {
        unsigned long long p = part[(long long)(bk * SPLIT + s) * NPB + tid];
        f0 += (int)(p & FMASK);
        f1 += (int)((p >> 21) & FMASK);
        f2 += (int)((p >> 42) & FMASK);
    }
    float4 self = xs[i];
    int degE = (int)self.w;
    const float inv = 1.0f / FSCALE;
    float a0 = (float)(f0 - FBIAS * degE) * inv + self.x;
    float a1 = (float)(f1 - FBIAS * degE) * inv + self.y;
    float a2 = (float)(f2 - FBIAS * degE) * inv + self.z;
    float di = dinv[i];
    a0 *= di; a1 *= di; a2 *= di;
    float g = 0.0f;
#pragma unroll
    for (int c = 0; c < 16; ++c) {
        float h = fmaf(a0, W1[c], fmaf(a1, W1[16 + c], fmaf(a2, W1[32 + c], b1[c])));
        h = fmaxf(h, 0.0f);
        g = fmaf(h, W2[c], g);
    }
    gs[i] = g * di;
}

__global__ void k_agg2P(const unsigned int* __restrict__ bin, const int* __restrict__ cursor,
                        const float* __restrict__ gs, float* __restrict__ part, int cap) {
    __shared__ float acc[NPB];
    const int tid = threadIdx.x;
    acc[tid] = 0.0f;
    __syncthreads();
    const int bk = blockIdx.x >> 3;
    const int sub = blockIdx.x & (SPLIT - 1);
    const int cnt = min(cursor[bk], cap);
    int lo, hi; sub_range(cnt, sub, &lo, &hi);
    const unsigned int* bp = bin + (long long)bk * cap;
    const int len = hi - lo, nvec = len >> 2;
    const uint4* bp4 = (const uint4*)(bp + lo);
    for (int v = tid; v < nvec; v += NPB) {
        uint4 q = bp4[v];
        float g0 = gs[q.x & 0x1FFFFu];
        float g1 = gs[q.y & 0x1FFFFu];
        float g2 = gs[q.z & 0x1FFFFu];
        float g3 = gs[q.w & 0x1FFFFu];
        atomicAdd(&acc[q.x >> 17], g0);
        atomicAdd(&acc[q.y >> 17], g1);
        atomicAdd(&acc[q.z >> 17], g2);
        atomicAdd(&acc[q.w >> 17], g3);
    }
    for (int k = lo + (nvec << 2) + tid; k < hi; k += NPB) {
        unsigned p = bp[k];
        atomicAdd(&acc[p >> 17], gs[p & 0x1FFFFu]);
    }
    __syncthreads();
    part[(long long)blockIdx.x * NPB + tid] = acc[tid];
}

__global__ void k_agg2C(const float* __restrict__ part, const float* __restrict__ dinv,
                        const float* __restrict__ gs, const float* __restrict__ b2,
                        float* __restrict__ out, int n) {
    const int tid = threadIdx.x;
    const int bk = blockIdx.x;
    const int i = bk * NPB + tid;
    if (i >= n) return;
    float acc = gs[i];
#pragma unroll
    for (int s = 0; s < SPLIT; ++s)
        acc += part[(long long)(bk * SPLIT + s) * NPB + tid];
    float z = dinv[i] * acc + b2[0];
    out[i] = 1.0f / (1.0f + expf(-z));
}

// ---------------- R1 fallback (small ws) ----------------
__global__ void k_detect(const int* e32, int* flag) {
    if (blockIdx.x == 0 && threadIdx.x == 0) {
        int is64 = 1;
        for (int k = 0; k < 16; ++k)
            if (e32[2 * k + 1] != 0) { is64 = 0; break; }
        *flag = is64;
    }
}
__global__ void f_init_deg(float* deg, int n) {
    int i = blockIdx.x * blockDim.x + threadIdx.x;
    if (i < n) deg[i] = 1.0f;
}
__global__ void f_deg(const void* edges, const int* flag, float* deg, long long E) {
    int is64 = *flag;
    long long e = (long long)blockIdx.x * blockDim.x + threadIdx.x;
    if (e < E) atomicAdd(&deg[load_idx(edges, E + e, is64)], 1.0f);
}
__global__ void f_dinv_xs(const float* x, const float* deg, float* dinv, float4* xs,
                          float4* agg3, int n) {
    int i = blockIdx.x * blockDim.x + threadIdx.x;
    if (i < n) {
        float di = rsqrtf(deg[i]);
        dinv[i] = di;
        float4 v = make_float4(x[3 * i] * di, x[3 * i + 1] * di, x[3 * i + 2] * di, 0.0f);
        xs[i] = v; agg3[i] = v;
    }
}
__global__ void f_edge1(const void* edges, const int* flag, const float4* xs,
                        float* agg3, long long E) {
    int is64 = *flag;
    long long e = (long long)blockIdx.x * blockDim.x + threadIdx.x;
    if (e < E) {
        long long s = load_idx(edges, e, is64);
        long long d = load_idx(edges, E + e, is64);
        float4 v = xs[s];
        atomicAdd(&agg3[4 * d + 0], v.x);
        atomicAdd(&agg3[4 * d + 1], v.y);
        atomicAdd(&agg3[4 * d + 2], v.z);
    }
}
__global__ void f_node1(const float* dinv, const float4* agg3, const float* W1,
                        const float* b1, const float* W2, float* gs, float* agg1, int n) {
    int i = blockIdx.x * blockDim.x + threadIdx.x;
    if (i < n) {
        float di = dinv[i];
        float4 a = agg3[i];
        float a0 = a.x * di, a1 = a.y * di, a2 = a.z * di;
        float g = 0.0f;
#pragma unroll
        for (int k = 0; k < 16; ++k) {
            float h = fmaf(a0, W1[k], fmaf(a1, W1[16 + k], fmaf(a2, W1[32 + k], b1[k])));
            h = fmaxf(h, 0.0f);
            g = fmaf(h, W2[k], g);
        }
        float v = g * di;
        gs[i] = v; agg1[i] = v;
    }
}
__global__ void f_edge2(const void* edges, const int* flag, const float* gs,
                        float* agg1, long long E) {
    int is64 = *flag;
    long long e = (long long)blockIdx.x * blockDim.x + threadIdx.x;
    if (e < E) atomicAdd(&agg1[load_idx(edges, E + e, is64)], gs[load_idx(edges, e, is64)]);
}
__global__ void f_final(const float* dinv, const float* agg1, const float* b2,
                        float* out, int n) {
    int i = blockIdx.x * blockDim.x + threadIdx.x;
    if (i < n) {
        float z = dinv[i] * agg1[i] + b2[0];
        out[i] = 1.0f / (1.0f + expf(-z));
    }
}

extern "C" void kernel_launch(void* const* d_in, const int* in_sizes, int n_in,
                              void* d_out, int out_size, void* d_ws, size_t ws_size,
                              hipStream_t stream) {
    const float* x  = (const float*)d_in[0];
    const void*  ei = d_in[1];
    const float* W1 = (const float*)d_in[2];
    const float* b1 = (const float*)d_in[3];
    const float* W2 = (const float*)d_in[4];
    const float* b2 = (const float*)d_in[5];
    float* out = (float*)d_out;

    long long n = in_sizes[0] / 3;   // 100000
    long long E = in_sizes[1] / 2;   // 3200000

    const int T = 256;
    const int gN = (int)((n + T - 1) / T);
    const int gE = (int)((E + T - 1) / T);

    int nb = (int)((n + NPB - 1) / NPB);                             // 391
    long long capll = (E / nb) + (E / nb) / 8 + 256;                 // mean + ~11 sigma
    int cap = (int)((capll + 63) / 64 * 64);
    size_t need = n * sizeof(float4)                                 // xs
                + (size_t)nb * SPLIT * NPB * sizeof(float4)          // part (aliased)
                + (size_t)nb * cap * sizeof(int)                     // bin
                + 2 * n * sizeof(float)                              // dinv, gs
                + nb * sizeof(int) + 128;                            // cursor, flag

    if (nb <= NB_MAX && n <= (1 << 17) && ws_size >= need) {
        char* p = (char*)d_ws;
        float4* xs   = (float4*)p;       p += n * sizeof(float4);
        char*  partb = p;                p += (size_t)nb * SPLIT * NPB * sizeof(float4);
        unsigned int* bin = (unsigned int*)p; p += (size_t)nb * cap * sizeof(int);
        float* dinv  = (float*)p;        p += n * sizeof(float);
        float* gs    = (float*)p;        p += n * sizeof(float);
        int*   cursor = (int*)p;         p += nb * sizeof(int);
        int*   flag  = (int*)p;

        // cooperative grid size: co-resident capacity at block=512
        int maxb = 0;
        hipError_t qerr = hipOccupancyMaxActiveBlocksPerMultiprocessor(&maxb, k_fused, T1, 0);
        if (qerr != hipSuccess || maxb < 1) maxb = 1;
        int G = maxb * 256;
        if (G > 1024) G = 1024;
        if (G < 64) G = 64;

        unsigned long long* partu = (unsigned long long*)partb;
        void* args[] = {
            (void*)&x, (void*)&ei, (void*)&W1, (void*)&b1, (void*)&W2, (void*)&b2,
            (void*)&out, (void*)&n, (void*)&E, (void*)&nb, (void*)&cap,
            (void*)&xs, (void*)&partu, (void*)&bin, (void*)&dinv, (void*)&gs,
            (void*)&cursor, (void*)&flag
        };
        hipError_t err = hipLaunchCooperativeKernel(k_fused, dim3(G), dim3(T1),
                                                    args, 0, stream);
        if (err != hipSuccess) {
            // R6 8-kernel pipeline (proven, 160 us)
            const long long per_blk = (long long)T1 * EPT;           // 4096 edges/block
            const int gB = (int)((E + per_blk - 1) / per_blk);       // 782
            k_zero_cursor<<<(nb + T - 1) / T, T, 0, stream>>>(cursor, nb, (const int*)ei, flag);
            k_bin<<<gB, T1, 0, stream>>>(ei, flag, cursor, bin, E, nb, cap);
            k_degP<<<nb * SPLIT, NPB, 0, stream>>>(bin, cursor, (int*)partb, cap);
            k_degC<<<nb, NPB, 0, stream>>>((const int*)partb, x, dinv, xs, (int)n);
            k_agg1P<<<nb * SPLIT, NPB, 0, stream>>>(bin, cursor, xs, (unsigned long long*)partb, cap);
            k_agg1C<<<nb, NPB, 0, stream>>>((const unsigned long long*)partb, dinv, xs, W1, b1, W2, gs, (int)n);
            k_agg2P<<<nb * SPLIT, NPB, 0, stream>>>(bin, cursor, gs, (float*)partb, cap);
            k_agg2C<<<nb, NPB, 0, stream>>>((const float*)partb, dinv, gs, b2, out, (int)n);
        }
    } else {
        // R1 proven atomic pipeline
        char* p = (char*)d_ws;
        float*  deg  = (float*)p;  p += n * sizeof(float);
        float*  dinv = (float*)p;  p += n * sizeof(float);
        float4* xs   = (float4*)p; p += n * sizeof(float4);
        float4* agg3 = (float4*)p; p += n * sizeof(float4);
        float*  gs   = (float*)p;  p += n * sizeof(float);
        float*  agg1 = (float*)p;  p += n * sizeof(float);
        int*    flag = (int*)p;

        k_detect<<<1, 64, 0, stream>>>((const int*)ei, flag);
        f_init_deg<<<gN, T, 0, stream>>>(deg, (int)n);
        f_deg<<<gE, T, 0, stream>>>(ei, flag, deg, E);
        f_dinv_xs<<<gN, T, 0, stream>>>(x, deg, dinv, xs, agg3, (int)n);
        f_edge1<<<gE, T, 0, stream>>>(ei, flag, xs, (float*)agg3, E);
        f_node1<<<gN, T, 0, stream>>>(dinv, agg3, W1, b1, W2, gs, agg1, (int)n);
        f_edge2<<<gE, T, 0, stream>>>(ei, flag, gs, agg1, E);
        f_final<<<gN, T, 0, stream>>>(dinv, agg1, b2, out, (int)n);
    }
}

// Round 8
// 165.386 us; speedup vs baseline: 2.3781x; 2.3781x over previous
//
#include <hip/hip_runtime.h>
#include <math.h>

// GCN 2-layer. R8: static-region binning — the fill's single LDS rtn atomic
// provides slot AND count; no histogram pass, no global reservation atomics.
// Consumers mask invalid slots of each (tile,bucket) 40-slot segment.
// (R7 coop fusion regressed 2.5x: bank conflicts + serialized phases. Reverted.)

#define NPB 256        // nodes per bucket (power of 2)
#define SHIFT 8        // log2(NPB)
#define NB_MAX 512     // max buckets supported by LDS hist in k_bin
#define SPLIT 8        // sub-tasks per bucket in partial kernels
#define T1 512         // threads per block in k_bin
#define EPT 8          // edges staged per thread in k_bin (tile = 4096 edges)
#define BCAP 40        // slots per (tile,bucket); mean 10.5, P(overflow)~1e-6/run
#define VPS 10         // uint4 vectors per segment (BCAP/4)
#define SEG_MAX 128    // max tile-segments per consumer task

#define FSCALE 1024.0f     // fixed-point scale (2^10)
#define FBIAS  8192        // per-addend bias (2^13)
#define FMASK  0x1FFFFFu   // 21-bit field mask

static __device__ __forceinline__ long long load_idx(const void* edges, long long pos, int is64) {
    if (is64) return ((const long long*)edges)[pos];
    return (long long)((const int*)edges)[pos];
}

static __device__ __forceinline__ unsigned long long pack3(float x, float y, float z) {
    unsigned long long e0 = (unsigned)(__float2int_rn(x * FSCALE) + FBIAS);
    unsigned long long e1 = (unsigned)(__float2int_rn(y * FSCALE) + FBIAS);
    unsigned long long e2 = (unsigned)(__float2int_rn(z * FSCALE) + FBIAS);
    return e0 | (e1 << 21) | (e2 << 42);
}

__global__ void k_detect(const int* e32, int* flag) {
    if (blockIdx.x == 0 && threadIdx.x == 0) {
        int is64 = 1;
        for (int k = 0; k < 16; ++k)
            if (e32[2 * k + 1] != 0) { is64 = 0; break; }
        *flag = is64;
    }
}

// Static-region binning: ONE LDS rtn atomic per edge. Block bid owns regions
// bin[(bid*nb+bk)*BCAP ...]; hist[bk] after the fill IS the count -> cnt.
__global__ void k_bin(const void* edges, const int* __restrict__ flag,
                      unsigned int* __restrict__ bin, int* __restrict__ cnt,
                      long long E, int nb) {
    __shared__ int hist[NB_MAX];
    const int tid = threadIdx.x;
    const int bid = blockIdx.x;
    for (int b = tid; b < nb; b += T1) hist[b] = 0;
    __syncthreads();

    const int is64 = *flag;
    const long long start = (long long)bid * (T1 * EPT);
    unsigned es[EPT], ed[EPT];
    if (is64) {
        const long long* e64 = (const long long*)edges;
#pragma unroll
        for (int j = 0; j < EPT; ++j) {
            long long e = start + j * T1 + tid;
            if (e < E) { es[j] = (unsigned)e64[e]; ed[j] = (unsigned)e64[E + e]; }
            else ed[j] = 0xFFFFFFFFu;
        }
    } else {
        const int* e32 = (const int*)edges;
#pragma unroll
        for (int j = 0; j < EPT; ++j) {
            long long e = start + j * T1 + tid;
            if (e < E) { es[j] = (unsigned)e32[e]; ed[j] = (unsigned)e32[E + e]; }
            else ed[j] = 0xFFFFFFFFu;
        }
    }

#pragma unroll
    for (int j = 0; j < EPT; ++j) {
        if (ed[j] == 0xFFFFFFFFu) continue;
        int bk = (int)(ed[j] >> SHIFT);
        int off = atomicAdd(&hist[bk], 1);          // slot AND count in one op
        if (off < BCAP)
            bin[((long long)bid * nb + bk) * BCAP + off] =
                ((ed[j] & (NPB - 1)) << 17) | es[j];
    }
    __syncthreads();
    for (int b = tid; b < nb; b += T1)
        cnt[(long long)bid * nb + b] = hist[b];      // coalesced
}

// ---- degree partial counts (masked segment reads) ----
__global__ void k_degP(const unsigned int* __restrict__ bin, const int* __restrict__ cnt,
                       int* __restrict__ part, int nb, int ntiles) {
    __shared__ int dcnt[NPB];
    __shared__ int cl[SEG_MAX];
    const int tid = threadIdx.x;
    const int bk = blockIdx.x >> 3;
    const int sub = blockIdx.x & (SPLIT - 1);
    const int t0 = sub * ntiles / SPLIT;
    const int t1 = (sub + 1) * ntiles / SPLIT;
    const int nseg = t1 - t0;
    dcnt[tid] = 0;
    for (int s = tid; s < nseg; s += NPB)
        cl[s] = min(cnt[(long long)(t0 + s) * nb + bk], BCAP);
    __syncthreads();
    const int nkv = nseg * VPS;
    for (int kv = tid; kv < nkv; kv += NPB) {
        int s = kv / VPS;
        int base4 = (kv - s * VPS) << 2;
        int c = cl[s];
        if (base4 >= c) continue;
        const uint4 q = *(const uint4*)(bin + ((long long)(t0 + s) * nb + bk) * BCAP + base4);
        atomicAdd(&dcnt[q.x >> 17], 1);
        if (base4 + 1 < c) atomicAdd(&dcnt[q.y >> 17], 1);
        if (base4 + 2 < c) atomicAdd(&dcnt[q.z >> 17], 1);
        if (base4 + 3 < c) atomicAdd(&dcnt[q.w >> 17], 1);
    }
    __syncthreads();
    part[(long long)blockIdx.x * NPB + tid] = dcnt[tid];
}

// combine -> dinv, pre-scaled xs (xs.w = edge-degree for agg1C bias fix)
__global__ void k_degC(const int* __restrict__ part, const float* __restrict__ x,
                       float* __restrict__ dinv, float4* __restrict__ xs, int n) {
    const int tid = threadIdx.x;
    const int bk = blockIdx.x;
    const int i = bk * NPB + tid;
    if (i >= n) return;
    int degE = 0;
#pragma unroll
    for (int s = 0; s < SPLIT; ++s)
        degE += part[(long long)(bk * SPLIT + s) * NPB + tid];
    float di = rsqrtf((float)degE + 1.0f);
    dinv[i] = di;
    xs[i] = make_float4(x[3 * i] * di, x[3 * i + 1] * di, x[3 * i + 2] * di, (float)degE);
}

// ---- layer 1: one packed u64 LDS atomic per edge ----
__global__ void k_agg1P(const unsigned int* __restrict__ bin, const int* __restrict__ cnt,
                        const float4* __restrict__ xs, unsigned long long* __restrict__ part,
                        int nb, int ntiles) {
    __shared__ unsigned long long acc[NPB];
    __shared__ int cl[SEG_MAX];
    const int tid = threadIdx.x;
    const int bk = blockIdx.x >> 3;
    const int sub = blockIdx.x & (SPLIT - 1);
    const int t0 = sub * ntiles / SPLIT;
    const int t1 = (sub + 1) * ntiles / SPLIT;
    const int nseg = t1 - t0;
    acc[tid] = 0ull;
    for (int s = tid; s < nseg; s += NPB)
        cl[s] = min(cnt[(long long)(t0 + s) * nb + bk], BCAP);
    __syncthreads();
    const int nkv = nseg * VPS;
    for (int kv = tid; kv < nkv; kv += NPB) {
        int s = kv / VPS;
        int base4 = (kv - s * VPS) << 2;
        int c = cl[s];
        if (base4 >= c) continue;
        const uint4 q = *(const uint4*)(bin + ((long long)(t0 + s) * nb + bk) * BCAP + base4);
        float4 v0 = xs[q.x & 0x1FFFFu];
        atomicAdd(&acc[q.x >> 17], pack3(v0.x, v0.y, v0.z));
        if (base4 + 1 < c) {
            float4 v = xs[q.y & 0x1FFFFu];
            atomicAdd(&acc[q.y >> 17], pack3(v.x, v.y, v.z));
        }
        if (base4 + 2 < c) {
            float4 v = xs[q.z & 0x1FFFFu];
            atomicAdd(&acc[q.z >> 17], pack3(v.x, v.y, v.z));
        }
        if (base4 + 3 < c) {
            float4 v = xs[q.w & 0x1FFFFu];
            atomicAdd(&acc[q.w >> 17], pack3(v.x, v.y, v.z));
        }
    }
    __syncthreads();
    part[(long long)blockIdx.x * NPB + tid] = acc[tid];
}

__global__ void k_agg1C(const unsigned long long* __restrict__ part,
                        const float* __restrict__ dinv, const float4* __restrict__ xs,
                        const float* __restrict__ W1, const float* __restrict__ b1,
                        const float* __restrict__ W2, float* __restrict__ gs, int n) {
    const int tid = threadIdx.x;
    const int bk = blockIdx.x;
    const int i = bk * NPB + tid;
    if (i >= n) return;
    int f0 = 0, f1 = 0, f2 = 0;
#pragma unroll
    for (int s = 0; s < SPLIT; ++s) {
        unsigned long long p = part[(long long)(bk * SPLIT + s) * NPB + tid];
        f0 += (int)(p & FMASK);
        f1 += (int)((p >> 21) & FMASK);
        f2 += (int)((p >> 42) & FMASK);
    }
    float4 self = xs[i];
    int degE = (int)self.w;
    const float inv = 1.0f / FSCALE;
    float a0 = (float)(f0 - FBIAS * degE) * inv + self.x;
    float a1 = (float)(f1 - FBIAS * degE) * inv + self.y;
    float a2 = (float)(f2 - FBIAS * degE) * inv + self.z;
    float di = dinv[i];
    a0 *= di; a1 *= di; a2 *= di;
    float g = 0.0f;
#pragma unroll
    for (int c = 0; c < 16; ++c) {   // W1 [3,16] row-major
        float h = fmaf(a0, W1[c], fmaf(a1, W1[16 + c], fmaf(a2, W1[32 + c], b1[c])));
        h = fmaxf(h, 0.0f);
        g = fmaf(h, W2[c], g);
    }
    gs[i] = g * di;   // pre-scaled by dinv for layer-2 src side
}

// ---- layer 2: scalar partial sums ----
__global__ void k_agg2P(const unsigned int* __restrict__ bin, const int* __restrict__ cnt,
                        const float* __restrict__ gs, float* __restrict__ part,
                        int nb, int ntiles) {
    __shared__ float acc[NPB];
    __shared__ int cl[SEG_MAX];
    const int tid = threadIdx.x;
    const int bk = blockIdx.x >> 3;
    const int sub = blockIdx.x & (SPLIT - 1);
    const int t0 = sub * ntiles / SPLIT;
    const int t1 = (sub + 1) * ntiles / SPLIT;
    const int nseg = t1 - t0;
    acc[tid] = 0.0f;
    for (int s = tid; s < nseg; s += NPB)
        cl[s] = min(cnt[(long long)(t0 + s) * nb + bk], BCAP);
    __syncthreads();
    const int nkv = nseg * VPS;
    for (int kv = tid; kv < nkv; kv += NPB) {
        int s = kv / VPS;
        int base4 = (kv - s * VPS) << 2;
        int c = cl[s];
        if (base4 >= c) continue;
        const uint4 q = *(const uint4*)(bin + ((long long)(t0 + s) * nb + bk) * BCAP + base4);
        atomicAdd(&acc[q.x >> 17], gs[q.x & 0x1FFFFu]);
        if (base4 + 1 < c) atomicAdd(&acc[q.y >> 17], gs[q.y & 0x1FFFFu]);
        if (base4 + 2 < c) atomicAdd(&acc[q.z >> 17], gs[q.z & 0x1FFFFu]);
        if (base4 + 3 < c) atomicAdd(&acc[q.w >> 17], gs[q.w & 0x1FFFFu]);
    }
    __syncthreads();
    part[(long long)blockIdx.x * NPB + tid] = acc[tid];
}

__global__ void k_agg2C(const float* __restrict__ part, const float* __restrict__ dinv,
                        const float* __restrict__ gs, const float* __restrict__ b2,
                        float* __restrict__ out, int n) {
    const int tid = threadIdx.x;
    const int bk = blockIdx.x;
    const int i = bk * NPB + tid;
    if (i >= n) return;
    float acc = gs[i];   // self-loop
#pragma unroll
    for (int s = 0; s < SPLIT; ++s)
        acc += part[(long long)(bk * SPLIT + s) * NPB + tid];
    float z = dinv[i] * acc + b2[0];
    out[i] = 1.0f / (1.0f + expf(-z));
}

// ---------------- R1 fallback (small ws) ----------------
__global__ void f_init_deg(float* deg, int n) {
    int i = blockIdx.x * blockDim.x + threadIdx.x;
    if (i < n) deg[i] = 1.0f;
}
__global__ void f_deg(const void* edges, const int* flag, float* deg, long long E) {
    int is64 = *flag;
    long long e = (long long)blockIdx.x * blockDim.x + threadIdx.x;
    if (e < E) atomicAdd(&deg[load_idx(edges, E + e, is64)], 1.0f);
}
__global__ void f_dinv_xs(const float* x, const float* deg, float* dinv, float4* xs,
                          float4* agg3, int n) {
    int i = blockIdx.x * blockDim.x + threadIdx.x;
    if (i < n) {
        float di = rsqrtf(deg[i]);
        dinv[i] = di;
        float4 v = make_float4(x[3 * i] * di, x[3 * i + 1] * di, x[3 * i + 2] * di, 0.0f);
        xs[i] = v; agg3[i] = v;
    }
}
__global__ void f_edge1(const void* edges, const int* flag, const float4* xs,
                        float* agg3, long long E) {
    int is64 = *flag;
    long long e = (long long)blockIdx.x * blockDim.x + threadIdx.x;
    if (e < E) {
        long long s = load_idx(edges, e, is64);
        long long d = load_idx(edges, E + e, is64);
        float4 v = xs[s];
        atomicAdd(&agg3[4 * d + 0], v.x);
        atomicAdd(&agg3[4 * d + 1], v.y);
        atomicAdd(&agg3[4 * d + 2], v.z);
    }
}
__global__ void f_node1(const float* dinv, const float4* agg3, const float* W1,
                        const float* b1, const float* W2, float* gs, float* agg1, int n) {
    int i = blockIdx.x * blockDim.x + threadIdx.x;
    if (i < n) {
        float di = dinv[i];
        float4 a = agg3[i];
        float a0 = a.x * di, a1 = a.y * di, a2 = a.z * di;
        float g = 0.0f;
#pragma unroll
        for (int k = 0; k < 16; ++k) {
            float h = fmaf(a0, W1[k], fmaf(a1, W1[16 + k], fmaf(a2, W1[32 + k], b1[k])));
            h = fmaxf(h, 0.0f);
            g = fmaf(h, W2[k], g);
        }
        float v = g * di;
        gs[i] = v; agg1[i] = v;
    }
}
__global__ void f_edge2(const void* edges, const int* flag, const float* gs,
                        float* agg1, long long E) {
    int is64 = *flag;
    long long e = (long long)blockIdx.x * blockDim.x + threadIdx.x;
    if (e < E) atomicAdd(&agg1[load_idx(edges, E + e, is64)], gs[load_idx(edges, e, is64)]);
}
__global__ void f_final(const float* dinv, const float* agg1, const float* b2,
                        float* out, int n) {
    int i = blockIdx.x * blockDim.x + threadIdx.x;
    if (i < n) {
        float z = dinv[i] * agg1[i] + b2[0];
        out[i] = 1.0f / (1.0f + expf(-z));
    }
}

extern "C" void kernel_launch(void* const* d_in, const int* in_sizes, int n_in,
                              void* d_out, int out_size, void* d_ws, size_t ws_size,
                              hipStream_t stream) {
    const float* x  = (const float*)d_in[0];
    const void*  ei = d_in[1];
    const float* W1 = (const float*)d_in[2];
    const float* b1 = (const float*)d_in[3];
    const float* W2 = (const float*)d_in[4];
    const float* b2 = (const float*)d_in[5];
    float* out = (float*)d_out;

    const long long n = in_sizes[0] / 3;   // 100000
    const long long E = in_sizes[1] / 2;   // 3200000

    const int T = 256;
    const int gN = (int)((n + T - 1) / T);
    const int gE = (int)((E + T - 1) / T);

    const int nb = (int)((n + NPB - 1) / NPB);                       // 391
    const long long per_tile = (long long)T1 * EPT;                  // 4096
    const int ntiles = (int)((E + per_tile - 1) / per_tile);         // 782
    const int max_nseg = (ntiles + SPLIT - 1) / SPLIT + 1;           // ~98

    size_t bin_bytes  = (size_t)ntiles * nb * BCAP * sizeof(int);    // ~49 MB
    size_t cnt_bytes  = ((size_t)ntiles * nb * sizeof(int) + 15) & ~(size_t)15;
    size_t part_bytes = (size_t)nb * SPLIT * NPB * sizeof(unsigned long long);
    size_t need = n * sizeof(float4) + part_bytes + bin_bytes + cnt_bytes
                + 2 * n * sizeof(float) + 64;

    if (nb <= NB_MAX && n <= (1 << 17) && max_nseg <= SEG_MAX && ws_size >= need) {
        char* p = (char*)d_ws;
        float4* xs   = (float4*)p;       p += n * sizeof(float4);
        char*  partb = p;                p += part_bytes;
        unsigned int* bin = (unsigned int*)p; p += bin_bytes;
        int*   cnt   = (int*)p;          p += cnt_bytes;
        float* dinv  = (float*)p;        p += n * sizeof(float);
        float* gs    = (float*)p;        p += n * sizeof(float);
        int*   flag  = (int*)p;

        k_detect<<<1, 64, 0, stream>>>((const int*)ei, flag);
        k_bin<<<ntiles, T1, 0, stream>>>(ei, flag, bin, cnt, E, nb);
        k_degP<<<nb * SPLIT, NPB, 0, stream>>>(bin, cnt, (int*)partb, nb, ntiles);
        k_degC<<<nb, NPB, 0, stream>>>((const int*)partb, x, dinv, xs, (int)n);
        k_agg1P<<<nb * SPLIT, NPB, 0, stream>>>(bin, cnt, xs, (unsigned long long*)partb, nb, ntiles);
        k_agg1C<<<nb, NPB, 0, stream>>>((const unsigned long long*)partb, dinv, xs, W1, b1, W2, gs, (int)n);
        k_agg2P<<<nb * SPLIT, NPB, 0, stream>>>(bin, cnt, gs, (float*)partb, nb, ntiles);
        k_agg2C<<<nb, NPB, 0, stream>>>((const float*)partb, dinv, gs, b2, out, (int)n);
    } else {
        // R1 proven atomic pipeline
        char* p = (char*)d_ws;
        float*  deg  = (float*)p;  p += n * sizeof(float);
        float*  dinv = (float*)p;  p += n * sizeof(float);
        float4* xs   = (float4*)p; p += n * sizeof(float4);
        float4* agg3 = (float4*)p; p += n * sizeof(float4);
        float*  gs   = (float*)p;  p += n * sizeof(float);
        float*  agg1 = (float*)p;  p += n * sizeof(float);
        int*    flag = (int*)p;

        k_detect<<<1, 64, 0, stream>>>((const int*)ei, flag);
        f_init_deg<<<gN, T, 0, stream>>>(deg, (int)n);
        f_deg<<<gE, T, 0, stream>>>(ei, flag, deg, E);
        f_dinv_xs<<<gN, T, 0, stream>>>(x, deg, dinv, xs, agg3, (int)n);
        f_edge1<<<gE, T, 0, stream>>>(ei, flag, xs, (float*)agg3, E);
        f_node1<<<gN, T, 0, stream>>>(dinv, agg3, W1, b1, W2, gs, agg1, (int)n);
        f_edge2<<<gE, T, 0, stream>>>(ei, flag, gs, agg1, E);
        f_final<<<gN, T, 0, stream>>>(dinv, agg1, b2, out, (int)n);
    }
}

// Round 9
// 156.637 us; speedup vs baseline: 2.5110x; 1.0558x over previous
//
#include <hip/hip_runtime.h>
#include <math.h>

// GCN 2-layer. R9 = R6 (proven 160us) + EPT 8->16 in k_bin (halves per-tile
// reservation/zero overhead; LDS ops/edge unchanged).
// Wall model: LDS-pipe instruction throughput ~5 cyc/instr/CU; pipeline does
// 5 LDS instrs/edge (bin:2, deg:1, agg1-u64:1, agg2:1) ~= 130us floor.

#define NPB 256        // nodes per bucket (power of 2)
#define SHIFT 8        // log2(NPB)
#define NB_MAX 512     // max buckets supported by LDS arrays in k_bin
#define SPLIT 8        // sub-blocks per bucket in partial kernels
#define T1 512         // threads per block in k_bin
#define EPT 16         // edges staged per thread in k_bin (tile = 8192 edges)

#define FSCALE 1024.0f     // fixed-point scale (2^10)
#define FBIAS  8192        // per-addend bias (2^13)
#define FMASK  0x1FFFFFu   // 21-bit field mask

static __device__ __forceinline__ long long load_idx(const void* edges, long long pos, int is64) {
    if (is64) return ((const long long*)edges)[pos];
    return (long long)((const int*)edges)[pos];
}

static __device__ __forceinline__ unsigned long long pack3(float x, float y, float z) {
    unsigned long long e0 = (unsigned)(__float2int_rn(x * FSCALE) + FBIAS);
    unsigned long long e1 = (unsigned)(__float2int_rn(y * FSCALE) + FBIAS);
    unsigned long long e2 = (unsigned)(__float2int_rn(z * FSCALE) + FBIAS);
    return e0 | (e1 << 21) | (e2 << 42);
}

// zero cursors + dtype-detect flag (merged)
__global__ void k_zero_cursor(int* cursor, int nb, const int* e32, int* flag) {
    int i = blockIdx.x * blockDim.x + threadIdx.x;
    if (i < nb) cursor[i] = 0;
    if (i == 0) {
        int is64 = 1;
        for (int k = 0; k < 16; ++k)
            if (e32[2 * k + 1] != 0) { is64 = 0; break; }
        *flag = is64;
    }
}

// Register-staged binning: ONE pass over the edge list; 2 LDS atomics/edge.
__global__ void k_bin(const void* edges, const int* __restrict__ flag,
                      int* __restrict__ cursor, unsigned int* __restrict__ bin,
                      long long E, int nb, int cap) {
    __shared__ int hist[NB_MAX];
    __shared__ int base[NB_MAX];
    const int tid = threadIdx.x;
    for (int b = tid; b < nb; b += T1) hist[b] = 0;
    __syncthreads();

    const int is64 = *flag;
    const long long start = (long long)blockIdx.x * ((long long)T1 * EPT);
    unsigned es[EPT], ed[EPT];

    if (is64) {
        const long long* e64 = (const long long*)edges;
#pragma unroll
        for (int j = 0; j < EPT; ++j) {
            long long e = start + j * T1 + tid;
            if (e < E) { es[j] = (unsigned)e64[e]; ed[j] = (unsigned)e64[E + e]; }
            else ed[j] = 0xFFFFFFFFu;
        }
    } else {
        const int* e32 = (const int*)edges;
#pragma unroll
        for (int j = 0; j < EPT; ++j) {
            long long e = start + j * T1 + tid;
            if (e < E) { es[j] = (unsigned)e32[e]; ed[j] = (unsigned)e32[E + e]; }
            else ed[j] = 0xFFFFFFFFu;
        }
    }

#pragma unroll
    for (int j = 0; j < EPT; ++j)
        if (ed[j] != 0xFFFFFFFFu) atomicAdd(&hist[ed[j] >> SHIFT], 1);
    __syncthreads();

    for (int b = tid; b < nb; b += T1) {
        int h = hist[b];
        base[b] = h ? atomicAdd(&cursor[b], h) : 0;
        hist[b] = 0;
    }
    __syncthreads();

#pragma unroll
    for (int j = 0; j < EPT; ++j) {
        if (ed[j] == 0xFFFFFFFFu) continue;
        int bk = (int)(ed[j] >> SHIFT);
        int off = base[bk] + atomicAdd(&hist[bk], 1);
        if (off < cap)
            bin[(long long)bk * cap + off] = ((ed[j] & (NPB - 1)) << 17) | es[j];
    }
}

static __device__ __forceinline__ void sub_range(int cnt, int sub, int* lo, int* hi) {
    int l = (int)(((long long)cnt * sub / SPLIT) & ~3LL);
    int h = (sub == SPLIT - 1) ? cnt : (int)(((long long)cnt * (sub + 1) / SPLIT) & ~3LL);
    *lo = l; *hi = h;
}

// ---- degree partial counts ----
__global__ void k_degP(const unsigned int* __restrict__ bin, const int* __restrict__ cursor,
                       int* __restrict__ part, int cap) {
    __shared__ int dcnt[NPB];
    const int tid = threadIdx.x;
    dcnt[tid] = 0;
    __syncthreads();
    const int bk = blockIdx.x >> 3;
    const int sub = blockIdx.x & (SPLIT - 1);
    const int cnt = min(cursor[bk], cap);
    int lo, hi; sub_range(cnt, sub, &lo, &hi);
    const unsigned int* bp = bin + (long long)bk * cap;
    const int len = hi - lo, nvec = len >> 2;
    const uint4* bp4 = (const uint4*)(bp + lo);
    for (int v = tid; v < nvec; v += NPB) {
        uint4 q = bp4[v];
        atomicAdd(&dcnt[q.x >> 17], 1);
        atomicAdd(&dcnt[q.y >> 17], 1);
        atomicAdd(&dcnt[q.z >> 17], 1);
        atomicAdd(&dcnt[q.w >> 17], 1);
    }
    for (int k = lo + (nvec << 2) + tid; k < hi; k += NPB)
        atomicAdd(&dcnt[bp[k] >> 17], 1);
    __syncthreads();
    part[(long long)blockIdx.x * NPB + tid] = dcnt[tid];
}

// combine -> dinv, pre-scaled xs (xs.w carries edge-degree for agg1C bias fix)
__global__ void k_degC(const int* __restrict__ part, const float* __restrict__ x,
                       float* __restrict__ dinv, float4* __restrict__ xs, int n) {
    const int tid = threadIdx.x;
    const int bk = blockIdx.x;
    const int i = bk * NPB + tid;
    if (i >= n) return;
    int degE = 0;
#pragma unroll
    for (int s = 0; s < SPLIT; ++s)
        degE += part[(long long)(bk * SPLIT + s) * NPB + tid];
    float di = rsqrtf((float)degE + 1.0f);
    dinv[i] = di;
    xs[i] = make_float4(x[3 * i] * di, x[3 * i + 1] * di, x[3 * i + 2] * di, (float)degE);
}

// ---- layer 1: ONE packed u64 LDS atomic per edge ----
__global__ void k_agg1P(const unsigned int* __restrict__ bin, const int* __restrict__ cursor,
                        const float4* __restrict__ xs, unsigned long long* __restrict__ part,
                        int cap) {
    __shared__ unsigned long long acc[NPB];
    const int tid = threadIdx.x;
    acc[tid] = 0ull;
    __syncthreads();
    const int bk = blockIdx.x >> 3;
    const int sub = blockIdx.x & (SPLIT - 1);
    const int cnt = min(cursor[bk], cap);
    int lo, hi; sub_range(cnt, sub, &lo, &hi);
    const unsigned int* bp = bin + (long long)bk * cap;
    const int len = hi - lo, nvec = len >> 2;
    const uint4* bp4 = (const uint4*)(bp + lo);
    for (int v = tid; v < nvec; v += NPB) {
        uint4 q = bp4[v];
        float4 v0 = xs[q.x & 0x1FFFFu];
        float4 v1 = xs[q.y & 0x1FFFFu];
        float4 v2 = xs[q.z & 0x1FFFFu];
        float4 v3 = xs[q.w & 0x1FFFFu];
        atomicAdd(&acc[q.x >> 17], pack3(v0.x, v0.y, v0.z));
        atomicAdd(&acc[q.y >> 17], pack3(v1.x, v1.y, v1.z));
        atomicAdd(&acc[q.z >> 17], pack3(v2.x, v2.y, v2.z));
        atomicAdd(&acc[q.w >> 17], pack3(v3.x, v3.y, v3.z));
    }
    for (int k = lo + (nvec << 2) + tid; k < hi; k += NPB) {
        unsigned p = bp[k];
        float4 v = xs[p & 0x1FFFFu];
        atomicAdd(&acc[p >> 17], pack3(v.x, v.y, v.z));
    }
    __syncthreads();
    part[(long long)blockIdx.x * NPB + tid] = acc[tid];
}

__global__ void k_agg1C(const unsigned long long* __restrict__ part,
                        const float* __restrict__ dinv, const float4* __restrict__ xs,
                        const float* __restrict__ W1, const float* __restrict__ b1,
                        const float* __restrict__ W2, float* __restrict__ gs, int n) {
    const int tid = threadIdx.x;
    const int bk = blockIdx.x;
    const int i = bk * NPB + tid;
    if (i >= n) return;
    int f0 = 0, f1 = 0, f2 = 0;
#pragma unroll
    for (int s = 0; s < SPLIT; ++s) {
        unsigned long long p = part[(long long)(bk * SPLIT + s) * NPB + tid];
        f0 += (int)(p & FMASK);
        f1 += (int)((p >> 21) & FMASK);
        f2 += (int)((p >> 42) & FMASK);
    }
    float4 self = xs[i];
    int degE = (int)self.w;
    const float inv = 1.0f / FSCALE;
    float a0 = (float)(f0 - FBIAS * degE) * inv + self.x;
    float a1 = (float)(f1 - FBIAS * degE) * inv + self.y;
    float a2 = (float)(f2 - FBIAS * degE) * inv + self.z;
    float di = dinv[i];
    a0 *= di; a1 *= di; a2 *= di;
    float g = 0.0f;
#pragma unroll
    for (int c = 0; c < 16; ++c) {   // W1 [3,16] row-major
        float h = fmaf(a0, W1[c], fmaf(a1, W1[16 + c], fmaf(a2, W1[32 + c], b1[c])));
        h = fmaxf(h, 0.0f);
        g = fmaf(h, W2[c], g);
    }
    gs[i] = g * di;   // pre-scaled by dinv for layer-2 src side
}

// ---- layer 2: scalar partial sums ----
__global__ void k_agg2P(const unsigned int* __restrict__ bin, const int* __restrict__ cursor,
                        const float* __restrict__ gs, float* __restrict__ part, int cap) {
    __shared__ float acc[NPB];
    const int tid = threadIdx.x;
    acc[tid] = 0.0f;
    __syncthreads();
    const int bk = blockIdx.x >> 3;
    const int sub = blockIdx.x & (SPLIT - 1);
    const int cnt = min(cursor[bk], cap);
    int lo, hi; sub_range(cnt, sub, &lo, &hi);
    const unsigned int* bp = bin + (long long)bk * cap;
    const int len = hi - lo, nvec = len >> 2;
    const uint4* bp4 = (const uint4*)(bp + lo);
    for (int v = tid; v < nvec; v += NPB) {
        uint4 q = bp4[v];
        float g0 = gs[q.x & 0x1FFFFu];
        float g1 = gs[q.y & 0x1FFFFu];
        float g2 = gs[q.z & 0x1FFFFu];
        float g3 = gs[q.w & 0x1FFFFu];
        atomicAdd(&acc[q.x >> 17], g0);
        atomicAdd(&acc[q.y >> 17], g1);
        atomicAdd(&acc[q.z >> 17], g2);
        atomicAdd(&acc[q.w >> 17], g3);
    }
    for (int k = lo + (nvec << 2) + tid; k < hi; k += NPB) {
        unsigned p = bp[k];
        atomicAdd(&acc[p >> 17], gs[p & 0x1FFFFu]);
    }
    __syncthreads();
    part[(long long)blockIdx.x * NPB + tid] = acc[tid];
}

__global__ void k_agg2C(const float* __restrict__ part, const float* __restrict__ dinv,
                        const float* __restrict__ gs, const float* __restrict__ b2,
                        float* __restrict__ out, int n) {
    const int tid = threadIdx.x;
    const int bk = blockIdx.x;
    const int i = bk * NPB + tid;
    if (i >= n) return;
    float acc = gs[i];   // self-loop
#pragma unroll
    for (int s = 0; s < SPLIT; ++s)
        acc += part[(long long)(bk * SPLIT + s) * NPB + tid];
    float z = dinv[i] * acc + b2[0];
    out[i] = 1.0f / (1.0f + expf(-z));
}

// ---------------- R1 fallback (small ws) ----------------
__global__ void k_detect(const int* e32, int* flag) {
    if (blockIdx.x == 0 && threadIdx.x == 0) {
        int is64 = 1;
        for (int k = 0; k < 16; ++k)
            if (e32[2 * k + 1] != 0) { is64 = 0; break; }
        *flag = is64;
    }
}
__global__ void f_init_deg(float* deg, int n) {
    int i = blockIdx.x * blockDim.x + threadIdx.x;
    if (i < n) deg[i] = 1.0f;
}
__global__ void f_deg(const void* edges, const int* flag, float* deg, long long E) {
    int is64 = *flag;
    long long e = (long long)blockIdx.x * blockDim.x + threadIdx.x;
    if (e < E) atomicAdd(&deg[load_idx(edges, E + e, is64)], 1.0f);
}
__global__ void f_dinv_xs(const float* x, const float* deg, float* dinv, float4* xs,
                          float4* agg3, int n) {
    int i = blockIdx.x * blockDim.x + threadIdx.x;
    if (i < n) {
        float di = rsqrtf(deg[i]);
        dinv[i] = di;
        float4 v = make_float4(x[3 * i] * di, x[3 * i + 1] * di, x[3 * i + 2] * di, 0.0f);
        xs[i] = v; agg3[i] = v;
    }
}
__global__ void f_edge1(const void* edges, const int* flag, const float4* xs,
                        float* agg3, long long E) {
    int is64 = *flag;
    long long e = (long long)blockIdx.x * blockDim.x + threadIdx.x;
    if (e < E) {
        long long s = load_idx(edges, e, is64);
        long long d = load_idx(edges, E + e, is64);
        float4 v = xs[s];
        atomicAdd(&agg3[4 * d + 0], v.x);
        atomicAdd(&agg3[4 * d + 1], v.y);
        atomicAdd(&agg3[4 * d + 2], v.z);
    }
}
__global__ void f_node1(const float* dinv, const float4* agg3, const float* W1,
                        const float* b1, const float* W2, float* gs, float* agg1, int n) {
    int i = blockIdx.x * blockDim.x + threadIdx.x;
    if (i < n) {
        float di = dinv[i];
        float4 a = agg3[i];
        float a0 = a.x * di, a1 = a.y * di, a2 = a.z * di;
        float g = 0.0f;
#pragma unroll
        for (int k = 0; k < 16; ++k) {
            float h = fmaf(a0, W1[k], fmaf(a1, W1[16 + k], fmaf(a2, W1[32 + k], b1[k])));
            h = fmaxf(h, 0.0f);
            g = fmaf(h, W2[k], g);
        }
        float v = g * di;
        gs[i] = v; agg1[i] = v;
    }
}
__global__ void f_edge2(const void* edges, const int* flag, const float* gs,
                        float* agg1, long long E) {
    int is64 = *flag;
    long long e = (long long)blockIdx.x * blockDim.x + threadIdx.x;
    if (e < E) atomicAdd(&agg1[load_idx(edges, E + e, is64)], gs[load_idx(edges, e, is64)]);
}
__global__ void f_final(const float* dinv, const float* agg1, const float* b2,
                        float* out, int n) {
    int i = blockIdx.x * blockDim.x + threadIdx.x;
    if (i < n) {
        float z = dinv[i] * agg1[i] + b2[0];
        out[i] = 1.0f / (1.0f + expf(-z));
    }
}

extern "C" void kernel_launch(void* const* d_in, const int* in_sizes, int n_in,
                              void* d_out, int out_size, void* d_ws, size_t ws_size,
                              hipStream_t stream) {
    const float* x  = (const float*)d_in[0];
    const void*  ei = d_in[1];
    const float* W1 = (const float*)d_in[2];
    const float* b1 = (const float*)d_in[3];
    const float* W2 = (const float*)d_in[4];
    const float* b2 = (const float*)d_in[5];
    float* out = (float*)d_out;

    const long long n = in_sizes[0] / 3;   // 100000
    const long long E = in_sizes[1] / 2;   // 3200000

    const int T = 256;
    const int gN = (int)((n + T - 1) / T);
    const int gE = (int)((E + T - 1) / T);

    const int nb = (int)((n + NPB - 1) / NPB);                       // 391
    long long capll = (E / nb) + (E / nb) / 8 + 256;                 // mean + ~11 sigma
    const int cap = (int)((capll + 63) / 64 * 64);
    size_t need = n * sizeof(float4)                                 // xs
                + (size_t)nb * SPLIT * NPB * sizeof(float4)          // part (aliased)
                + (size_t)nb * cap * sizeof(int)                     // bin
                + 2 * n * sizeof(float)                              // dinv, gs
                + nb * sizeof(int) + 128;                            // cursor, flag

    if (nb <= NB_MAX && n <= (1 << 17) && ws_size >= need) {
        char* p = (char*)d_ws;
        float4* xs   = (float4*)p;       p += n * sizeof(float4);
        char*  partb = p;                p += (size_t)nb * SPLIT * NPB * sizeof(float4);
        unsigned int* bin = (unsigned int*)p; p += (size_t)nb * cap * sizeof(int);
        float* dinv  = (float*)p;        p += n * sizeof(float);
        float* gs    = (float*)p;        p += n * sizeof(float);
        int*   cursor = (int*)p;         p += nb * sizeof(int);
        int*   flag  = (int*)p;

        const long long per_blk = (long long)T1 * EPT;               // 8192 edges/block
        const int gB = (int)((E + per_blk - 1) / per_blk);           // 391

        k_zero_cursor<<<(nb + T - 1) / T, T, 0, stream>>>(cursor, nb, (const int*)ei, flag);
        k_bin<<<gB, T1, 0, stream>>>(ei, flag, cursor, bin, E, nb, cap);
        k_degP<<<nb * SPLIT, NPB, 0, stream>>>(bin, cursor, (int*)partb, cap);
        k_degC<<<nb, NPB, 0, stream>>>((const int*)partb, x, dinv, xs, (int)n);
        k_agg1P<<<nb * SPLIT, NPB, 0, stream>>>(bin, cursor, xs, (unsigned long long*)partb, cap);
        k_agg1C<<<nb, NPB, 0, stream>>>((const unsigned long long*)partb, dinv, xs, W1, b1, W2, gs, (int)n);
        k_agg2P<<<nb * SPLIT, NPB, 0, stream>>>(bin, cursor, gs, (float*)partb, cap);
        k_agg2C<<<nb, NPB, 0, stream>>>((const float*)partb, dinv, gs, b2, out, (int)n);
    } else {
        // R1 proven atomic pipeline
        char* p = (char*)d_ws;
        float*  deg  = (float*)p;  p += n * sizeof(float);
        float*  dinv = (float*)p;  p += n * sizeof(float);
        float4* xs   = (float4*)p; p += n * sizeof(float4);
        float4* agg3 = (float4*)p; p += n * sizeof(float4);
        float*  gs   = (float*)p;  p += n * sizeof(float);
        float*  agg1 = (float*)p;  p += n * sizeof(float);
        int*    flag = (int*)p;

        k_detect<<<1, 64, 0, stream>>>((const int*)ei, flag);
        f_init_deg<<<gN, T, 0, stream>>>(deg, (int)n);
        f_deg<<<gE, T, 0, stream>>>(ei, flag, deg, E);
        f_dinv_xs<<<gN, T, 0, stream>>>(x, deg, dinv, xs, agg3, (int)n);
        f_edge1<<<gE, T, 0, stream>>>(ei, flag, xs, (float*)agg3, E);
        f_node1<<<gN, T, 0, stream>>>(dinv, agg3, W1, b1, W2, gs, agg1, (int)n);
        f_edge2<<<gE, T, 0, stream>>>(ei, flag, gs, agg1, E);
        f_final<<<gN, T, 0, stream>>>(dinv, agg1, b2, out, (int)n);
    }
}